// Round 10
// baseline (76.265 us; speedup 1.0000x reference)
//
#include <hip/hip_runtime.h>
#include <hip/hip_bf16.h>
#include <stdint.h>

#define BATCH 8192
#define DIM   1024
#define BM 128
#define BN 64
#define BK 64
#define NT 16

typedef __attribute__((ext_vector_type(4))) float f32x4;
typedef __attribute__((ext_vector_type(8))) short bf16x8;
typedef __attribute__((ext_vector_type(4))) unsigned short u16x4;
typedef __attribute__((ext_vector_type(8))) unsigned short u16x8;

#define AS1(p) ((const __attribute__((address_space(1))) void*)(p))
#define AS3(p) ((__attribute__((address_space(3))) void*)(p))

__device__ __forceinline__ unsigned short f2bf(float f) {
    union { __hip_bfloat16 h; unsigned short u; } v;
    v.h = __hip_bfloat16(f);
    return v.u;
}

__device__ __forceinline__ float sigma_f(float x) {
    float x2 = x * x;
    return x2 * __builtin_amdgcn_rcpf(1.0f + x2);
}

// ---------------------------------------------------------------------------
// Kernel 1: convert A (f32 [D][D]) to bf16
// ---------------------------------------------------------------------------
__global__ __launch_bounds__(256) void convA_kernel(
    const float* __restrict__ A, unsigned short* __restrict__ Ab)
{
    int idx = blockIdx.x * 256 + threadIdx.x;
    f32x4 av = ((const f32x4*)A)[idx];
    u16x4 ab;
#pragma unroll
    for (int i = 0; i < 4; ++i) ab[i] = f2bf(av[i]);
    ((u16x4*)Ab)[idx] = ab;
}

// ---------------------------------------------------------------------------
// Kernel 2: producer/consumer WAVE-SPECIALIZED fused kernel.
//   512 thr = 8 waves: waves 0-3 = GEMM (pure ds_read+MFMA, no vmem, no
//   waits -> barrier arrival never blocked on memory); waves 4-7 = streamers
//   (B global_load_lds, sigma(x)->A-tile LDS, base-pass: x/ex/W -> base LDS).
//   Raw s_barrier per K-step (NO vmcnt drain). Per-wave vmcnt => streamer
//   latency never stalls GEMM waves; B-glds drain is implied by the
//   compiler's in-order wait on the later-issued sigma x-loads.
//   Tile 128x64. LDS: dbuf 2x{A 16K|B 8K}=48K + base f32[128][64]=32K = 80K
//   -> 2 blocks/CU. Epilogue: C dump -> LDS, then out0/1/2 stores only
//   (base and C both read from LDS). HBM traffic = the 196 MB floor.
// ---------------------------------------------------------------------------
__global__ __launch_bounds__(512, 4) void fused_kernel(
    const float* __restrict__ x, const float* __restrict__ ex,
    const float* __restrict__ W, const float* __restrict__ tgt,
    const unsigned short* __restrict__ Ab,
    float* __restrict__ out0, float* __restrict__ out1,
    float* __restrict__ out2)
{
    __shared__ __align__(16) char lds[81920];
    char* baseL = lds + 49152;                   // base f32[128][64]

    // ---- block mapping: 16 bn of one bm-group per XCD (x L2-hot)
    const int b     = blockIdx.x;
    const int xcd   = b & 7;
    const int local = b >> 3;                    // 0..127
    const int bm    = xcd * 8 + (local >> 4);    // 0..63
    const int bn    = local & 15;                // 0..15

    const int tid  = threadIdx.x;
    const int lane = tid & 63;
    const int wid  = tid >> 6;                   // 0..7
    const int l15  = lane & 15;

    f32x4 acc[4][2];
#pragma unroll
    for (int mi = 0; mi < 4; ++mi)
#pragma unroll
        for (int ni = 0; ni < 2; ++ni)
            acc[mi][ni] = f32x4{0.f, 0.f, 0.f, 0.f};

    // streamer base-pass pipeline registers (live across steps)
    f32x4 bx = {}, bev = {}, bwv = {};

    // ---------------- prologue: streamers stage tile 0 into buf0
    if (wid >= 4) {
        const int sw  = wid - 4;                 // 0..3
        const int st  = tid - 256;               // 0..255
        const int swz = (((lane & 7) ^ (lane >> 3)) << 4);
        const char* gB0 = (const char*)Ab +
            ((size_t)(bn * BN + sw * 16 + (lane >> 3)) * DIM) * 2 + swz;
#pragma unroll
        for (int j = 0; j < 2; ++j)
            __builtin_amdgcn_global_load_lds(
                AS1(gB0 + (size_t)j * (8 * DIM * 2)),
                AS3(lds + 16384 + (sw * 16 + j * 8) * 128), 16, 0, 0);
#pragma unroll
        for (int a = 0; a < 4; ++a) {
            const int idx = a * 256 + st;
            const int row = idx >> 3, g = idx & 7;
            const float* gxs = x + (size_t)(bm * BM + row) * DIM + g * 8;
            f32x4 v0 = *(const f32x4*)gxs;
            f32x4 v1 = *(const f32x4*)(gxs + 4);
            u16x8 sb;
#pragma unroll
            for (int i = 0; i < 4; ++i) {
                sb[i]     = f2bf(sigma_f(v0[i]));
                sb[i + 4] = f2bf(sigma_f(v1[i]));
            }
            *(u16x8*)(lds + row * 128 + ((g * 16) ^ ((row & 7) << 4))) = sb;
        }
    }
    __syncthreads();

    // ---------------- main K loop: raw barriers, no vmem drain
    for (int t = 0; t < NT; ++t) {
        if (wid < 4) {
            // ======== GEMM waves: pure LDS->MFMA, zero vmem ========
            const int wr = wid >> 1, wc = wid & 1;
            const int rd_sw = (lane & 7) << 4;
            const int cb0   = (lane >> 4) << 4;
            const char* As_ = lds + (t & 1) * 24576;
            const char* Bs_ = As_ + 16384;
#pragma unroll
            for (int kk = 0; kk < 2; ++kk) {
                bf16x8 af[4], bfr[2];
#pragma unroll
                for (int mi = 0; mi < 4; ++mi)
                    af[mi] = *(const bf16x8*)(As_ + (wr * 64 + mi * 16 + l15) * 128 +
                                              ((cb0 + kk * 64) ^ rd_sw));
#pragma unroll
                for (int ni = 0; ni < 2; ++ni)
                    bfr[ni] = *(const bf16x8*)(Bs_ + (wc * 32 + ni * 16 + l15) * 128 +
                                               ((cb0 + kk * 64) ^ rd_sw));
#pragma unroll
                for (int mi = 0; mi < 4; ++mi)
#pragma unroll
                    for (int ni = 0; ni < 2; ++ni)
                        acc[mi][ni] = __builtin_amdgcn_mfma_f32_16x16x32_bf16(
                            af[mi], bfr[ni], acc[mi][ni], 0, 0, 0);
            }
        } else {
            // ======== streamer waves: staging + base-pass ========
            const int sw  = wid - 4;
            const int st  = tid - 256;
            char* nbuf = lds + ((t + 1) & 1) * 24576;
            const int kn = (t + 1) * BK;

            // 1) B(t+1) glds FIRST (oldest in this wave's vmcnt queue)
            if (t + 1 < NT) {
                const int swz = (((lane & 7) ^ (lane >> 3)) << 4);
                const char* gB = (const char*)Ab +
                    ((size_t)(bn * BN + sw * 16 + (lane >> 3)) * DIM) * 2 + swz +
                    (size_t)kn * 2;
#pragma unroll
                for (int j = 0; j < 2; ++j)
                    __builtin_amdgcn_global_load_lds(
                        AS1(gB + (size_t)j * (8 * DIM * 2)),
                        AS3(nbuf + 16384 + (sw * 16 + j * 8) * 128), 16, 0, 0);
            }
            __builtin_amdgcn_sched_barrier(0);   // keep B oldest

            // 2) x loads for sigma(t+1) (compiler waits these -> drains B too)
            f32x4 xs[4][2];
            if (t + 1 < NT) {
#pragma unroll
                for (int a = 0; a < 4; ++a) {
                    const int idx = a * 256 + st;
                    const int row = idx >> 3, g = idx & 7;
                    const float* gxs = x + (size_t)(bm * BM + row) * DIM + g * 8 + kn;
                    xs[a][0] = *(const f32x4*)gxs;
                    xs[a][1] = *(const f32x4*)(gxs + 4);
                }
            }

            // 3) base-pass pipeline: even step = issue loads, odd = compute
            const int p   = t >> 1;
            const int row = p * 16 + (st >> 4);
            const int cv  = st & 15;
            const size_t v4 = (size_t)(bm * BM + row) * (DIM / 4) + bn * 16 + cv;
            if (!(t & 1)) {
                bx  = ((const f32x4*)x)[v4];
                bev = ((const f32x4*)ex)[v4];
                bwv = ((const f32x4*)W)[v4];
            } else {
                f32x4 tv = ((const f32x4*)tgt)[bn * 16 + cv];
                f32x4 bq;
#pragma unroll
                for (int e = 0; e < 4; ++e) {
                    float xi = bx[e], ti = tv[e];
                    float ba = ti * ti * __builtin_amdgcn_rcpf(1.0f + ti * ti);
                    float u  = -(bwv[e] * (xi + bev[e] - ti)) * ba;
                    float s  = sigma_f(xi);
                    bq[e] = -xi + u * s;
                }
                *(f32x4*)(baseL + row * 256 + cv * 16) = bq;
            }

            // 4) sigma(t+1) -> A(nbuf)
            if (t + 1 < NT) {
#pragma unroll
                for (int a = 0; a < 4; ++a) {
                    const int idx = a * 256 + st;
                    const int arow = idx >> 3, g = idx & 7;
                    u16x8 sb;
#pragma unroll
                    for (int i = 0; i < 4; ++i) {
                        sb[i]     = f2bf(sigma_f(xs[a][0][i]));
                        sb[i + 4] = f2bf(sigma_f(xs[a][1][i]));
                    }
                    *(u16x8*)(nbuf + arow * 128 + ((g * 16) ^ ((arow & 7) << 4))) = sb;
                }
            }
        }
        // common tail: publish LDS, raw barrier (NO vmcnt drain)
        asm volatile("s_waitcnt lgkmcnt(0)" ::: "memory");
        __builtin_amdgcn_sched_barrier(0);
        __builtin_amdgcn_s_barrier();
        __builtin_amdgcn_sched_barrier(0);
    }

    // ---------------- C dump (GEMM waves) into [0,32K)
    if (wid < 4) {
        const int wr = wid >> 1, wc = wid & 1;
#pragma unroll
        for (int mi = 0; mi < 4; ++mi)
#pragma unroll
            for (int ni = 0; ni < 2; ++ni) {
                const int row_ = wr * 64 + mi * 16 + ((lane >> 4) << 2);
                const int col  = wc * 32 + ni * 16 + l15;
#pragma unroll
                for (int r = 0; r < 4; ++r)
                    *(float*)(lds + (row_ + r) * 256 + col * 4) = acc[mi][ni][r];
            }
    }
    __syncthreads();

    // ---------------- final epilogue: all 8 waves, LDS -> out0/1/2
#pragma unroll
    for (int i = 0; i < 4; ++i) {
        const int q   = i * 512 + tid;           // 0..2047
        const int row = q >> 4;                  // 0..127
        const int cv  = q & 15;                  // 0..15
        f32x4 c  = *(const f32x4*)(lds  + row * 256 + cv * 16);
        f32x4 bq = *(const f32x4*)(baseL + row * 256 + cv * 16);
        const size_t v4 = (size_t)(bm * BM + row) * (DIM / 4) + bn * 16 + cv;
        f32x4 o0 = bq + c;
        ((f32x4*)out0)[v4] = o0;
        ((f32x4*)out1)[v4] = -o0;
        ((f32x4*)out2)[v4] = f32x4{0.f, 0.f, 0.f, 0.f};
    }
}

// ---------------------------------------------------------------------------
extern "C" void kernel_launch(void* const* d_in, const int* in_sizes, int n_in,
                              void* d_out, int out_size, void* d_ws, size_t ws_size,
                              hipStream_t stream)
{
    const float* x   = (const float*)d_in[0];
    const float* ex  = (const float*)d_in[1];
    const float* W   = (const float*)d_in[2];
    const float* A   = (const float*)d_in[3];
    const float* tgt = (const float*)d_in[4];

    float* out0 = (float*)d_out;
    float* out1 = out0 + (size_t)BATCH * DIM;
    float* out2 = out1 + (size_t)BATCH * DIM;

    unsigned short* Abf = (unsigned short*)d_ws;   // 2 MiB

    convA_kernel<<<DIM * DIM / 4 / 256, 256, 0, stream>>>(A, Abf);
    fused_kernel<<<(BATCH / BM) * (DIM / BN), 512, 0, stream>>>(
        x, ex, W, tgt, Abf, out0, out1, out2);
}